// Round 1
// baseline (520.995 us; speedup 1.0000x reference)
//
#include <hip/hip_runtime.h>

typedef unsigned short u16;
typedef short bf16x8 __attribute__((ext_vector_type(8)));
typedef float floatx4 __attribute__((ext_vector_type(4)));

// ---------- bf16 helpers (bit-level RNE) --------------------------------------
static __device__ __forceinline__ u16 f2bf(float f) {
  unsigned int u = __float_as_uint(f);
  unsigned int lsb = (u >> 16) & 1u;
  u += 0x7FFFu + lsb;                 // round-to-nearest-even
  return (u16)(u >> 16);
}
static __device__ __forceinline__ float bf2f(u16 u) {
  return __uint_as_float(((unsigned int)u) << 16);
}

// ---------- async global->LDS, 16B per lane (dest = uniform base + lane*16) ----
static __device__ __forceinline__ void gl_lds16(const u16* g, u16* l) {
  __builtin_amdgcn_global_load_lds(
      (const __attribute__((address_space(1))) void*)g,
      (__attribute__((address_space(3))) void*)l, 16, 0, 0);
}

// ---------- unified prep: weight transposes + bias concat + x split/transpose --
__global__ __launch_bounds__(256)
void prep_all(const float* __restrict__ wq, const float* __restrict__ wk,
              const float* __restrict__ wv, const float* __restrict__ wp,
              const float* __restrict__ bq, const float* __restrict__ bk,
              const float* __restrict__ x,
              u16* __restrict__ qkThi, u16* __restrict__ qkTlo,
              u16* __restrict__ wvThi, u16* __restrict__ wpThi,
              float* __restrict__ bqk,
              u16* __restrict__ xhi, u16* __restrict__ xlo,
              u16* __restrict__ xThi) {
  __shared__ float t[32][33];
  const int z = blockIdx.z;
  const int tid = threadIdx.x;
  const int lr = tid >> 3;            // 0..31
  const int lc = (tid & 7) * 4;       // 0,4,..,28

  if (z == 4) {
    if (blockIdx.y == 0 && blockIdx.x < 8) {
      const int i = blockIdx.x * 256 + tid;
      bqk[i] = (i < 1024) ? bq[i] : bk[i - 1024];
    }
    return;
  }

  if (z >= 5) {
    const int r0 = ((z - 5) * 32 + blockIdx.y) * 32;
    const int c0 = blockIdx.x * 32;
    float4 v = *(const float4*)(x + (size_t)(r0 + lr) * 1024 + c0 + lc);
    float f[4] = {v.x, v.y, v.z, v.w};
    t[lr][lc + 0] = v.x; t[lr][lc + 1] = v.y; t[lr][lc + 2] = v.z; t[lr][lc + 3] = v.w;
    u16 ph[4], pl[4];
#pragma unroll
    for (int j = 0; j < 4; j++) {
      ph[j] = f2bf(f[j]);
      pl[j] = f2bf(f[j] - bf2f(ph[j]));
    }
    const size_t o = (size_t)(r0 + lr) * 1024 + c0 + lc;
    *(uint2*)(xhi + o) = *(uint2*)ph;
    *(uint2*)(xlo + o) = *(uint2*)pl;
    __syncthreads();
    u16 pt[4];
#pragma unroll
    for (int j = 0; j < 4; j++) pt[j] = f2bf(t[lc + j][lr]);
    const int b = r0 >> 11, rt = r0 & 2047;
    *(uint2*)(xThi + (size_t)b * (1024 * 2048) + (size_t)(c0 + lr) * 2048 + rt + lc) =
        *(uint2*)pt;
    return;
  }

  // weight transposes (z 0..3)
  const float* in = (z == 0) ? wq : (z == 1) ? wk : (z == 2) ? wv : wp;
  u16* hi = (z == 2) ? wvThi : (z == 3) ? wpThi : (qkThi + (size_t)z * 1024 * 1024);
  u16* lo = (z == 0) ? qkTlo : (z == 1) ? (qkTlo + 1024 * 1024) : (u16*)nullptr;
  const int want_lo = (z < 2);

  const int r0 = blockIdx.y * 32, c0 = blockIdx.x * 32;
  float4 v = *(const float4*)(in + (size_t)(r0 + lr) * 1024 + c0 + lc);
  t[lr][lc + 0] = v.x; t[lr][lc + 1] = v.y; t[lr][lc + 2] = v.z; t[lr][lc + 3] = v.w;
  __syncthreads();
  u16 ph[4], pl[4];
#pragma unroll
  for (int j = 0; j < 4; j++) {
    float f = t[lc + j][lr];
    ph[j] = f2bf(f);
    if (want_lo) pl[j] = f2bf(f - bf2f(ph[j]));
  }
  const size_t o = (size_t)(c0 + lr) * 1024 + r0 + lc;
  *(uint2*)(hi + o) = *(uint2*)ph;
  if (want_lo) *(uint2*)(lo + o) = *(uint2*)pl;
}

// ---------- MFMA GEMM, m97 structure (kept for px / ctx / output GEMMs) --------
template<int KB, int ASP, int BSP, int OM, int HB>
__global__ __launch_bounds__(256)
void gemm_mfma(const u16* __restrict__ Ahi, const u16* __restrict__ Alo,
               const u16* __restrict__ Bhi, const u16* __restrict__ Blo,
               const float* __restrict__ bias,
               void* __restrict__ C0, void* __restrict__ C1,
               void* __restrict__ C2, void* __restrict__ C3,
               int N, int K, int lda, int ldb, int ldc,
               long long aB, long long bB, long long cB, float scale) {
  constexpr int CM = KB / 8 - 1;
  constexpr int RPI = 512 / KB;
  constexpr int NI = KB / 16;
  constexpr int PL = 128 * KB;
  __shared__ __align__(16) u16 As[(1 + ASP) * PL];
  __shared__ __align__(16) u16 Bs[(1 + BSP) * PL];

  const int bz = blockIdx.z;
  const u16* A0 = Ahi + (size_t)bz * aB;
  const u16* A1 = ASP ? (Alo + (size_t)bz * aB) : (const u16*)nullptr;
  const u16* B0 = Bhi + (size_t)bz * bB;
  const u16* B1 = BSP ? (Blo + (size_t)bz * bB) : (const u16*)nullptr;

  const int m0 = blockIdx.y * 128;
  const int n0 = blockIdx.x * 128;
  const int tid = threadIdx.x;
  const int w = tid >> 6;
  const int L = tid & 63;
  const int rr = L & 15, quad = L >> 4;
  const int wm = (w >> 1) * 64, wn = (w & 1) * 64;

  const int lrow = (KB == 32) ? (L >> 2) : (L >> 3);
  const int c3 = (L & CM) ^ ((L >> 3) & CM);
  const int srow = w * 32 + lrow;
  u16* stA = &As[w * 32 * KB];
  u16* stB = &Bs[w * 32 * KB];
  const u16* gA0 = A0 + (size_t)(m0 + srow) * lda + c3 * 8;
  const u16* gA1 = ASP ? A1 + (size_t)(m0 + srow) * lda + c3 * 8 : (const u16*)nullptr;
  const u16* gB0 = B0 + (size_t)(n0 + srow) * ldb + c3 * 8;
  const u16* gB1 = BSP ? B1 + (size_t)(n0 + srow) * ldb + c3 * 8 : (const u16*)nullptr;

  floatx4 acc[4][4] = {};

  for (int k0 = 0; k0 < K; k0 += KB) {
#pragma unroll
    for (int q = 0; q < NI; q++) {
      gl_lds16(gA0 + k0 + (size_t)q * RPI * lda, stA + q * 512);
      gl_lds16(gB0 + k0 + (size_t)q * RPI * ldb, stB + q * 512);
    }
    if (ASP) {
#pragma unroll
      for (int q = 0; q < NI; q++)
        gl_lds16(gA1 + k0 + (size_t)q * RPI * lda, stA + PL + q * 512);
    }
    if (BSP) {
#pragma unroll
      for (int q = 0; q < NI; q++)
        gl_lds16(gB1 + k0 + (size_t)q * RPI * ldb, stB + PL + q * 512);
    }
    __syncthreads();

#pragma unroll
    for (int s = 0; s < KB / 32; s++) {
      const int pcb = ((KB == 32) ? (quad ^ ((rr >> 1) & 3))
                                  : ((s * 4 + quad) ^ (rr & 7))) * 8;
      bf16x8 a0[4], a1[4], b0[4], b1[4];
#pragma unroll
      for (int i = 0; i < 4; i++) {
        const int arow = wm + i * 16 + rr;
        const int brow = wn + i * 16 + rr;
        a0[i] = *(const bf16x8*)&As[arow * KB + pcb];
        b0[i] = *(const bf16x8*)&Bs[brow * KB + pcb];
        if (ASP) a1[i] = *(const bf16x8*)&As[PL + arow * KB + pcb];
        if (BSP) b1[i] = *(const bf16x8*)&Bs[PL + brow * KB + pcb];
      }
#pragma unroll
      for (int i = 0; i < 4; i++) {
#pragma unroll
        for (int j = 0; j < 4; j++) {
          acc[i][j] = __builtin_amdgcn_mfma_f32_16x16x32_bf16(a0[i], b0[j], acc[i][j], 0, 0, 0);
          if (ASP && BSP) {
            acc[i][j] = __builtin_amdgcn_mfma_f32_16x16x32_bf16(a0[i], b1[j], acc[i][j], 0, 0, 0);
            acc[i][j] = __builtin_amdgcn_mfma_f32_16x16x32_bf16(a1[i], b0[j], acc[i][j], 0, 0, 0);
          }
        }
      }
    }
    __syncthreads();
  }

#pragma unroll
  for (int i = 0; i < 4; i++) {
    const int mbase = m0 + wm + i * 16 + quad * 4;
#pragma unroll
    for (int j = 0; j < 4; j++) {
      const int col = n0 + wn + j * 16 + rr;
      float bvs = 0.f;
      if (HB) bvs = bias[col];
      if (OM == 5) {
        u16* hi; u16* lo;
        if (col < 1024) { hi = (u16*)C0; lo = (u16*)C1; }
        else            { hi = (u16*)C2; lo = (u16*)C3; }
        const int cc = col & 1023;
#pragma unroll
        for (int ii = 0; ii < 4; ii++) {
          const float v = acc[i][j][ii] + bvs;
          const size_t idx = (size_t)(mbase + ii) * 1024 + cc;
          const u16 h = f2bf(v);
          hi[idx] = h;
          lo[idx] = f2bf(v - bf2f(h));
        }
      } else {
        u16* Cb = (u16*)C0 + (size_t)bz * cB;
        float* Cf = (float*)C0 + (size_t)bz * cB;
        u16* Cl = (OM == 1) ? ((u16*)C1 + (size_t)bz * cB) : (u16*)nullptr;
#pragma unroll
        for (int ii = 0; ii < 4; ii++) {
          const float v = acc[i][j][ii] * scale + bvs;
          const size_t idx = (size_t)(mbase + ii) * ldc + col;
          if (OM == 0) {
            Cb[idx] = f2bf(v);
          } else if (OM == 1) {
            const u16 h = f2bf(v);
            Cb[idx] = h;
            Cl[idx] = f2bf(v - bf2f(h));
          } else {
            Cf[idx] = v;
          }
        }
      }
    }
  }
}

// ---------- 256x256 8-phase GEMM (T2+T3+T4+T5), 3-term split via K-extension ---
// C[M,N] = Ahi.Bhi^T + Ahi.Blo^T + Alo.Bhi^T, A/B stored [rows][1024] bf16.
// K_eff = 3072 = 48 K-tiles of 64, each as 2 k-halves of 32 (pairs H = 0..95).
// LDS: per-operand ring of 4 half-slots [256 rows][32], XOR swizzle chunk^=row&3
// (2-way bank aliasing = free). Staging: A-half H at phase 2H-5, B-half H at
// 2H-4 (slot frees at 2H-6) -> steady-state s_waitcnt vmcnt(6) once per pair.
// Per phase: ds_read subtile | stage 1 half (2x gl_lds) | bar | lgkmcnt(0) |
// setprio(1) 16 MFMA setprio(0) | bar.  OM=5: routed planar split out (Q|K).
// OM=2: fp32 out * scale (scores), ldc=2048.
template<int OM>
__global__ __launch_bounds__(512, 2)
void gemm8(const u16* __restrict__ Ahi, const u16* __restrict__ Alo,
           const u16* __restrict__ Bhi, const u16* __restrict__ Blo,
           const float* __restrict__ bias,
           void* __restrict__ C0, void* __restrict__ C1,
           void* __restrict__ C2, void* __restrict__ C3,
           long long aB, long long bB, long long cB, float scale) {
  __shared__ __align__(16) u16 As[4 * 8192];   // 64 KB: A k-half ring
  __shared__ __align__(16) u16 Bs[4 * 8192];   // 64 KB: B k-half ring

  // bijective XCD swizzle on flattened id (nwg % 8 == 0 for both call sites)
  const int gx = gridDim.x, gy = gridDim.y, gz = gridDim.z;
  const int flat = blockIdx.x + gx * (blockIdx.y + gy * blockIdx.z);
  const int nwg = gx * gy * gz;
  const int lg = (flat & 7) * (nwg >> 3) + (flat >> 3);
  const int bx = lg % gx;
  const int by = (lg / gx) % gy;
  const int bz = lg / (gx * gy);

  const int m0 = by * 256, n0 = bx * 256;
  const u16* pAhi = Ahi + (size_t)bz * aB;
  const u16* pAlo = Alo + (size_t)bz * aB;
  const u16* pBhi = Bhi + (size_t)bz * bB;
  const u16* pBlo = Blo + (size_t)bz * bB;

  const int tid = threadIdx.x;
  const int w = tid >> 6;             // wave 0..7
  const int L = tid & 63;
  const int rr = L & 15, quad = L >> 4;
  const int wm = (w >> 2) * 128;      // 0 / 128
  const int wn = (w & 3) * 64;        // 0 / 64 / 128 / 192

  // staging: lane covers row (L>>2) of its wave's 16-row stripe, phys chunk L&3;
  // pre-swizzled global source chunk = (L&3) ^ (row&3)  [rule #21: swz source]
  const int rbase = w * 16 + (L >> 2);
  const int coff = (((L & 3) ^ ((L >> 2) & 3)) << 3);
  const int arow = (m0 + rbase) * 1024 + coff;  // elem offset within one plane
  const int brow = (n0 + rbase) * 1024 + coff;
  u16* const ldA = As + w * 512;                // wave-uniform LDS dest base
  u16* const ldB = Bs + w * 512;

  // frag reads: row*32 + (quad ^ (row&3))*8 ; row&3 == rr&3 for all frags
  const int aoff = ((wm + rr) << 5) + ((quad ^ (rr & 3)) << 3);
  const int boff = ((wn + rr) << 5) + ((quad ^ (rr & 3)) << 3);

  auto stageA = [&](int H) {
    const int kt = H >> 1;
    const u16* src = (kt < 32) ? pAhi : pAlo;           // terms: hh, hl -> Ahi; lh -> Alo
    const int koff = ((kt & 15) << 6) + ((H & 1) << 5);
    const u16* g = src + arow + koff;
    u16* l = ldA + (H & 3) * 8192;
    gl_lds16(g, l);
    gl_lds16(g + 128 * 1024, l + 4096);
  };
  auto stageB = [&](int H) {
    const int kt = H >> 1;
    const u16* src = (kt < 16) ? pBhi : (kt < 32) ? pBlo : pBhi;
    const int koff = ((kt & 15) << 6) + ((H & 1) << 5);
    const u16* g = src + brow + koff;
    u16* l = ldB + (H & 3) * 8192;
    gl_lds16(g, l);
    gl_lds16(g + 128 * 1024, l + 4096);
  };

  floatx4 acc[8][4] = {};

#define PAIR(H, SB2, SA3, VM)                                                  \
  {                                                                            \
    __builtin_amdgcn_sched_barrier(0);                                         \
    const u16* ab = As + ((H) & 3) * 8192 + aoff;                              \
    const u16* bb = Bs + ((H) & 3) * 8192 + boff;                              \
    bf16x8 a[8], b0, b1, b2, b3;                                               \
    _Pragma("unroll")                                                          \
    for (int i = 0; i < 8; i++) a[i] = *(const bf16x8*)(ab + i * 512);         \
    b0 = *(const bf16x8*)(bb);                                                 \
    b1 = *(const bf16x8*)(bb + 512);                                           \
    if (SB2) stageB((H) + 2);                                                  \
    __builtin_amdgcn_s_barrier();                                              \
    asm volatile("s_waitcnt lgkmcnt(0)");                                      \
    __builtin_amdgcn_s_setprio(1);                                             \
    _Pragma("unroll")                                                          \
    for (int i = 0; i < 8; i++) {                                              \
      acc[i][0] = __builtin_amdgcn_mfma_f32_16x16x32_bf16(a[i], b0, acc[i][0], 0, 0, 0); \
      acc[i][1] = __builtin_amdgcn_mfma_f32_16x16x32_bf16(a[i], b1, acc[i][1], 0, 0, 0); \
    }                                                                          \
    __builtin_amdgcn_s_setprio(0);                                             \
    __builtin_amdgcn_s_barrier();                                              \
    b2 = *(const bf16x8*)(bb + 1024);                                          \
    b3 = *(const bf16x8*)(bb + 1536);                                          \
    if (SA3) stageA((H) + 3);                                                  \
    __builtin_amdgcn_s_barrier();                                              \
    asm volatile("s_waitcnt lgkmcnt(0)");                                      \
    __builtin_amdgcn_s_setprio(1);                                             \
    _Pragma("unroll")                                                          \
    for (int i = 0; i < 8; i++) {                                              \
      acc[i][2] = __builtin_amdgcn_mfma_f32_16x16x32_bf16(a[i], b2, acc[i][2], 0, 0, 0); \
      acc[i][3] = __builtin_amdgcn_mfma_f32_16x16x32_bf16(a[i], b3, acc[i][3], 0, 0, 0); \
    }                                                                          \
    __builtin_amdgcn_s_setprio(0);                                             \
    if ((VM) == 6) asm volatile("s_waitcnt vmcnt(6)");                         \
    else if ((VM) == 4) asm volatile("s_waitcnt vmcnt(4)");                    \
    else if ((VM) == 0) asm volatile("s_waitcnt vmcnt(0)");                    \
    __builtin_amdgcn_s_barrier();                                              \
  }

  // prologue: issue order A0,B0,A1,B1,A2 -> 3 halves (6 loads) stay in flight
  stageA(0); stageB(0); stageA(1); stageB(1); stageA(2);
  asm volatile("s_waitcnt vmcnt(6)");
  __builtin_amdgcn_s_barrier();

  for (int H = 0; H <= 92; ++H)
    PAIR(H, true, true, 6);
  PAIR(93, true, false, 4);           // stages B(95) only; drain to 4
  PAIR(94, false, false, 0);          // drain to 0 (guarantees A(95),B(95))
  PAIR(95, false, false, -1);         // last pair, nothing to wait for
#undef PAIR

  // epilogue: D[row = quad*4+ii][col = rr] per 16x16 fragment (m89-verified)
#pragma unroll
  for (int i = 0; i < 8; i++) {
    const int mb = m0 + wm + i * 16 + quad * 4;
#pragma unroll
    for (int j = 0; j < 4; j++) {
      const int col = n0 + wn + j * 16 + rr;
      if (OM == 5) {
        u16* hi; u16* lo;
        if (col < 1024) { hi = (u16*)C0; lo = (u16*)C1; }
        else            { hi = (u16*)C2; lo = (u16*)C3; }
        const int cc = col & 1023;
        const float bvs = bias[col];
#pragma unroll
        for (int ii = 0; ii < 4; ii++) {
          const float v = acc[i][j][ii] + bvs;
          const size_t idx = (size_t)(mb + ii) * 1024 + cc;
          const u16 h = f2bf(v);
          hi[idx] = h;
          lo[idx] = f2bf(v - bf2f(h));
        }
      } else {
        float* Cf = (float*)C0 + (size_t)bz * cB;
#pragma unroll
        for (int ii = 0; ii < 4; ii++)
          Cf[(size_t)(mb + ii) * 2048 + col] = acc[i][j][ii] * scale;
      }
    }
  }
}

// ---------- row softmax over 2048 fp32 scores, in place + bf16 copy ------------
__global__ __launch_bounds__(256)
void softmax_rows(float* __restrict__ S, u16* __restrict__ Pb) {
  const int row = blockIdx.x;
  float* s = S + (size_t)row * 2048;
  const int tid = threadIdx.x;
  const int w = tid >> 6;
  __shared__ float redm[4];
  __shared__ float reds[4];

  float v[8];
  float mx = -1e30f;
#pragma unroll
  for (int i = 0; i < 8; i++) {
    v[i] = s[tid + 256 * i];
    mx = fmaxf(mx, v[i]);
  }
#pragma unroll
  for (int o = 32; o > 0; o >>= 1) mx = fmaxf(mx, __shfl_xor(mx, o, 64));
  if ((tid & 63) == 0) redm[w] = mx;
  __syncthreads();
  mx = fmaxf(fmaxf(redm[0], redm[1]), fmaxf(redm[2], redm[3]));

  float sum = 0.f;
#pragma unroll
  for (int i = 0; i < 8; i++) {
    v[i] = __expf(v[i] - mx);
    sum += v[i];
  }
#pragma unroll
  for (int o = 32; o > 0; o >>= 1) sum += __shfl_xor(sum, o, 64);
  if ((tid & 63) == 0) reds[w] = sum;
  __syncthreads();
  sum = reds[0] + reds[1] + reds[2] + reds[3];
  const float rs = 1.0f / sum;
#pragma unroll
  for (int i = 0; i < 8; i++) {
    const float p = v[i] * rs;
    s[tid + 256 * i] = p;
    Pb[(size_t)row * 2048 + tid + 256 * i] = f2bf(p);
  }
}

// ---------- launch ------------------------------------------------------------
extern "C" void kernel_launch(void* const* d_in, const int* in_sizes, int n_in,
                              void* d_out, int out_size, void* d_ws, size_t ws_size,
                              hipStream_t stream) {
  const float* x  = (const float*)d_in[0];
  const float* wq = (const float*)d_in[1];
  const float* bq = (const float*)d_in[2];
  const float* wk = (const float*)d_in[3];
  const float* bk = (const float*)d_in[4];
  const float* wv = (const float*)d_in[5];
  const float* bv = (const float*)d_in[6];
  const float* wp = (const float*)d_in[7];
  const float* bp = (const float*)d_in[8];

  const size_t MB = 1024 * 1024;
  char* ws = (char*)d_ws;
  u16* qkThi = (u16*)(ws + 0 * MB);          // [2048][1024] bf16, 4 MB
  u16* qkTlo = (u16*)(ws + 4 * MB);          // 4 MB
  u16* wvThi = (u16*)(ws + 8 * MB);          // 2 MB
  u16* wpThi = (u16*)(ws + 10 * MB);         // 2 MB
  float* bqk = (float*)(ws + 12 * MB);       // 8 KB
  u16* xhi   = (u16*)(ws + 13 * MB);         // 16 MB each (8192x1024 bf16)
  u16* xlo   = (u16*)(ws + 29 * MB);
  u16* qhi   = (u16*)(ws + 45 * MB);
  u16* qlo   = (u16*)(ws + 61 * MB);
  u16* khi   = (u16*)(ws + 77 * MB);
  u16* klo   = (u16*)(ws + 93 * MB);
  u16* xThi  = (u16*)(ws + 109 * MB);        // [b][1024][2048] bf16, 16 MB
  u16* pbf   = khi;                          // overlay: k dead after scores
  u16* px    = qhi;                          // overlay: q dead after scores
  u16* ctx   = qlo;                          // overlay

  float* outp = (float*)d_out;               // [4,2048,1024] fp32
  float* scf  = (float*)d_out + 8388608;     // scores -> softmax in place

  const dim3 blk(256);

  // prep: weights + bias + x split/transpose, one launch
  prep_all<<<dim3(32, 32, 13), blk, 0, stream>>>(
      wq, wk, wv, wp, bq, bk, x, qkThi, qkTlo, wvThi, wpThi, bqk, xhi, xlo, xThi);

  // fused Q|K projection: 256^2 8-phase, K-extended 3-term split, routed planar
  // split outputs. 256 blocks = 1/CU.
  gemm8<5><<<dim3(8, 32, 1), dim3(512), 0, stream>>>(
      xhi, xlo, qkThi, qkTlo, bqk, qhi, qlo, khi, klo, 0, 0, 0, 1.0f);

  // scores = (q . k) * 32, 256^2 8-phase, fp32 into d_out's p region
  gemm8<2><<<dim3(8, 8, 4), dim3(512), 0, stream>>>(
      qhi, qlo, khi, klo, nullptr, scf, nullptr, nullptr, nullptr,
      2048LL * 1024, 2048LL * 1024, 2048LL * 2048, 32.0f);

  // softmax rows: fp32 p in place (d_out) + bf16 p
  softmax_rows<<<dim3(8192), blk, 0, stream>>>(scf, pbf);

  // px = p @ x   (reassociation: ctx = (p@x)@wv + bv since rows of p sum to 1)
  gemm_mfma<64, 0, 0, 0, 0><<<dim3(8, 16, 4), blk, 0, stream>>>(
      pbf, nullptr, xThi, nullptr, nullptr, px, nullptr, nullptr, nullptr,
      1024, 2048, 2048, 2048, 1024,
      2048LL * 2048, 1024LL * 2048, 2048LL * 1024, 1.0f);

  // ctx = px @ wv + bv (bf16 out)
  gemm_mfma<64, 0, 0, 0, 1><<<dim3(8, 64, 1), blk, 0, stream>>>(
      px, nullptr, wvThi, nullptr, bv, ctx, nullptr, nullptr, nullptr,
      1024, 1024, 1024, 1024, 1024, 0, 0, 0, 1.0f);

  // output = ctx @ wp + bp, fp32 out
  gemm_mfma<64, 0, 0, 2, 1><<<dim3(8, 64, 1), blk, 0, stream>>>(
      ctx, nullptr, wpThi, nullptr, bp, outp, nullptr, nullptr, nullptr,
      1024, 1024, 1024, 1024, 1024, 0, 0, 0, 1.0f);
}

// Round 2
// 453.759 us; speedup vs baseline: 1.1482x; 1.1482x over previous
//
#include <hip/hip_runtime.h>

typedef unsigned short u16;
typedef short bf16x8 __attribute__((ext_vector_type(8)));
typedef float floatx4 __attribute__((ext_vector_type(4)));

// ---------- bf16 helpers (bit-level RNE) --------------------------------------
static __device__ __forceinline__ u16 f2bf(float f) {
  unsigned int u = __float_as_uint(f);
  unsigned int lsb = (u >> 16) & 1u;
  u += 0x7FFFu + lsb;                 // round-to-nearest-even
  return (u16)(u >> 16);
}
static __device__ __forceinline__ float bf2f(u16 u) {
  return __uint_as_float(((unsigned int)u) << 16);
}

// ---------- async global->LDS, 16B per lane (dest = uniform base + lane*16) ----
static __device__ __forceinline__ void gl_lds16(const u16* g, u16* l) {
  __builtin_amdgcn_global_load_lds(
      (const __attribute__((address_space(1))) void*)g,
      (__attribute__((address_space(3))) void*)l, 16, 0, 0);
}

// ---------- unified prep: weight transposes + bias concat + x split/transpose --
__global__ __launch_bounds__(256)
void prep_all(const float* __restrict__ wq, const float* __restrict__ wk,
              const float* __restrict__ wv, const float* __restrict__ wp,
              const float* __restrict__ bq, const float* __restrict__ bk,
              const float* __restrict__ x,
              u16* __restrict__ qkThi, u16* __restrict__ qkTlo,
              u16* __restrict__ wvThi, u16* __restrict__ wpThi,
              float* __restrict__ bqk,
              u16* __restrict__ xhi, u16* __restrict__ xlo,
              u16* __restrict__ xThi) {
  __shared__ float t[32][33];
  const int z = blockIdx.z;
  const int tid = threadIdx.x;
  const int lr = tid >> 3;            // 0..31
  const int lc = (tid & 7) * 4;       // 0,4,..,28

  if (z == 4) {
    if (blockIdx.y == 0 && blockIdx.x < 8) {
      const int i = blockIdx.x * 256 + tid;
      bqk[i] = (i < 1024) ? bq[i] : bk[i - 1024];
    }
    return;
  }

  if (z >= 5) {
    const int r0 = ((z - 5) * 32 + blockIdx.y) * 32;
    const int c0 = blockIdx.x * 32;
    float4 v = *(const float4*)(x + (size_t)(r0 + lr) * 1024 + c0 + lc);
    float f[4] = {v.x, v.y, v.z, v.w};
    t[lr][lc + 0] = v.x; t[lr][lc + 1] = v.y; t[lr][lc + 2] = v.z; t[lr][lc + 3] = v.w;
    u16 ph[4], pl[4];
#pragma unroll
    for (int j = 0; j < 4; j++) {
      ph[j] = f2bf(f[j]);
      pl[j] = f2bf(f[j] - bf2f(ph[j]));
    }
    const size_t o = (size_t)(r0 + lr) * 1024 + c0 + lc;
    *(uint2*)(xhi + o) = *(uint2*)ph;
    *(uint2*)(xlo + o) = *(uint2*)pl;
    __syncthreads();
    u16 pt[4];
#pragma unroll
    for (int j = 0; j < 4; j++) pt[j] = f2bf(t[lc + j][lr]);
    const int b = r0 >> 11, rt = r0 & 2047;
    *(uint2*)(xThi + (size_t)b * (1024 * 2048) + (size_t)(c0 + lr) * 2048 + rt + lc) =
        *(uint2*)pt;
    return;
  }

  // weight transposes (z 0..3)
  const float* in = (z == 0) ? wq : (z == 1) ? wk : (z == 2) ? wv : wp;
  u16* hi = (z == 2) ? wvThi : (z == 3) ? wpThi : (qkThi + (size_t)z * 1024 * 1024);
  u16* lo = (z == 0) ? qkTlo : (z == 1) ? (qkTlo + 1024 * 1024) : (u16*)nullptr;
  const int want_lo = (z < 2);

  const int r0 = blockIdx.y * 32, c0 = blockIdx.x * 32;
  float4 v = *(const float4*)(in + (size_t)(r0 + lr) * 1024 + c0 + lc);
  t[lr][lc + 0] = v.x; t[lr][lc + 1] = v.y; t[lr][lc + 2] = v.z; t[lr][lc + 3] = v.w;
  __syncthreads();
  u16 ph[4], pl[4];
#pragma unroll
  for (int j = 0; j < 4; j++) {
    float f = t[lc + j][lr];
    ph[j] = f2bf(f);
    if (want_lo) pl[j] = f2bf(f - bf2f(ph[j]));
  }
  const size_t o = (size_t)(c0 + lr) * 1024 + r0 + lc;
  *(uint2*)(hi + o) = *(uint2*)ph;
  if (want_lo) *(uint2*)(lo + o) = *(uint2*)pl;
}

// ---------- MFMA GEMM, m97 structure (kept for px / ctx / output GEMMs) --------
template<int KB, int ASP, int BSP, int OM, int HB>
__global__ __launch_bounds__(256)
void gemm_mfma(const u16* __restrict__ Ahi, const u16* __restrict__ Alo,
               const u16* __restrict__ Bhi, const u16* __restrict__ Blo,
               const float* __restrict__ bias,
               void* __restrict__ C0, void* __restrict__ C1,
               void* __restrict__ C2, void* __restrict__ C3,
               int N, int K, int lda, int ldb, int ldc,
               long long aB, long long bB, long long cB, float scale) {
  constexpr int CM = KB / 8 - 1;
  constexpr int RPI = 512 / KB;
  constexpr int NI = KB / 16;
  constexpr int PL = 128 * KB;
  __shared__ __align__(16) u16 As[(1 + ASP) * PL];
  __shared__ __align__(16) u16 Bs[(1 + BSP) * PL];

  const int bz = blockIdx.z;
  const u16* A0 = Ahi + (size_t)bz * aB;
  const u16* A1 = ASP ? (Alo + (size_t)bz * aB) : (const u16*)nullptr;
  const u16* B0 = Bhi + (size_t)bz * bB;
  const u16* B1 = BSP ? (Blo + (size_t)bz * bB) : (const u16*)nullptr;

  const int m0 = blockIdx.y * 128;
  const int n0 = blockIdx.x * 128;
  const int tid = threadIdx.x;
  const int w = tid >> 6;
  const int L = tid & 63;
  const int rr = L & 15, quad = L >> 4;
  const int wm = (w >> 1) * 64, wn = (w & 1) * 64;

  const int lrow = (KB == 32) ? (L >> 2) : (L >> 3);
  const int c3 = (L & CM) ^ ((L >> 3) & CM);
  const int srow = w * 32 + lrow;
  u16* stA = &As[w * 32 * KB];
  u16* stB = &Bs[w * 32 * KB];
  const u16* gA0 = A0 + (size_t)(m0 + srow) * lda + c3 * 8;
  const u16* gA1 = ASP ? A1 + (size_t)(m0 + srow) * lda + c3 * 8 : (const u16*)nullptr;
  const u16* gB0 = B0 + (size_t)(n0 + srow) * ldb + c3 * 8;
  const u16* gB1 = BSP ? B1 + (size_t)(n0 + srow) * ldb + c3 * 8 : (const u16*)nullptr;

  floatx4 acc[4][4] = {};

  for (int k0 = 0; k0 < K; k0 += KB) {
#pragma unroll
    for (int q = 0; q < NI; q++) {
      gl_lds16(gA0 + k0 + (size_t)q * RPI * lda, stA + q * 512);
      gl_lds16(gB0 + k0 + (size_t)q * RPI * ldb, stB + q * 512);
    }
    if (ASP) {
#pragma unroll
      for (int q = 0; q < NI; q++)
        gl_lds16(gA1 + k0 + (size_t)q * RPI * lda, stA + PL + q * 512);
    }
    if (BSP) {
#pragma unroll
      for (int q = 0; q < NI; q++)
        gl_lds16(gB1 + k0 + (size_t)q * RPI * ldb, stB + PL + q * 512);
    }
    __syncthreads();

#pragma unroll
    for (int s = 0; s < KB / 32; s++) {
      const int pcb = ((KB == 32) ? (quad ^ ((rr >> 1) & 3))
                                  : ((s * 4 + quad) ^ (rr & 7))) * 8;
      bf16x8 a0[4], a1[4], b0[4], b1[4];
#pragma unroll
      for (int i = 0; i < 4; i++) {
        const int arow = wm + i * 16 + rr;
        const int brow = wn + i * 16 + rr;
        a0[i] = *(const bf16x8*)&As[arow * KB + pcb];
        b0[i] = *(const bf16x8*)&Bs[brow * KB + pcb];
        if (ASP) a1[i] = *(const bf16x8*)&As[PL + arow * KB + pcb];
        if (BSP) b1[i] = *(const bf16x8*)&Bs[PL + brow * KB + pcb];
      }
#pragma unroll
      for (int i = 0; i < 4; i++) {
#pragma unroll
        for (int j = 0; j < 4; j++) {
          acc[i][j] = __builtin_amdgcn_mfma_f32_16x16x32_bf16(a0[i], b0[j], acc[i][j], 0, 0, 0);
          if (ASP && BSP) {
            acc[i][j] = __builtin_amdgcn_mfma_f32_16x16x32_bf16(a0[i], b1[j], acc[i][j], 0, 0, 0);
            acc[i][j] = __builtin_amdgcn_mfma_f32_16x16x32_bf16(a1[i], b0[j], acc[i][j], 0, 0, 0);
          }
        }
      }
    }
    __syncthreads();
  }

#pragma unroll
  for (int i = 0; i < 4; i++) {
    const int mbase = m0 + wm + i * 16 + quad * 4;
#pragma unroll
    for (int j = 0; j < 4; j++) {
      const int col = n0 + wn + j * 16 + rr;
      float bvs = 0.f;
      if (HB) bvs = bias[col];
      if (OM == 5) {
        u16* hi; u16* lo;
        if (col < 1024) { hi = (u16*)C0; lo = (u16*)C1; }
        else            { hi = (u16*)C2; lo = (u16*)C3; }
        const int cc = col & 1023;
#pragma unroll
        for (int ii = 0; ii < 4; ii++) {
          const float v = acc[i][j][ii] + bvs;
          const size_t idx = (size_t)(mbase + ii) * 1024 + cc;
          const u16 h = f2bf(v);
          hi[idx] = h;
          lo[idx] = f2bf(v - bf2f(h));
        }
      } else {
        u16* Cb = (u16*)C0 + (size_t)bz * cB;
        float* Cf = (float*)C0 + (size_t)bz * cB;
        u16* Cl = (OM == 1) ? ((u16*)C1 + (size_t)bz * cB) : (u16*)nullptr;
#pragma unroll
        for (int ii = 0; ii < 4; ii++) {
          const float v = acc[i][j][ii] * scale + bvs;
          const size_t idx = (size_t)(mbase + ii) * ldc + col;
          if (OM == 0) {
            Cb[idx] = f2bf(v);
          } else if (OM == 1) {
            const u16 h = f2bf(v);
            Cb[idx] = h;
            Cl[idx] = f2bf(v - bf2f(h));
          } else {
            Cf[idx] = v;
          }
        }
      }
    }
  }
}

// ---------- 256x256 8-phase GEMM (T2+T3+T4+T5), 3-term split via K-extension ---
// C[M,N] = Ahi.Bhi^T + Ahi.Blo^T + Alo.Bhi^T, A/B stored [rows][1024] bf16.
// K_eff = 3072 = 48 K-tiles of 64, each as 2 k-halves of 32 (pairs H = 0..95).
// LDS: per-operand ring of 4 half-slots [256 rows][32 cols] bf16 (row = 64 B).
// Swizzle (R1 fix): phys chunk = logical ^ ((row>>1)&3) -> frag-read bank group
// g = 4*(rr&1) + (quad ^ ((rr>>1)&3)) covers all 8 groups 2x per quarter-wave
// (2-way = free, m136). Prior row&3 variant left half the banks idle (4-way,
// 9.4M conflicts). Staging source is inverse-swizzled (rule #21), LDS linear.
// Staging: B-half H+2 at phase 1 of pair H, A-half H+3 at phase 2 -> steady
// state s_waitcnt vmcnt(6) once per pair, never 0 in the main loop.
template<int OM>
__global__ __launch_bounds__(512, 2)
void gemm8(const u16* __restrict__ Ahi, const u16* __restrict__ Alo,
           const u16* __restrict__ Bhi, const u16* __restrict__ Blo,
           const float* __restrict__ bias,
           void* __restrict__ C0, void* __restrict__ C1,
           void* __restrict__ C2, void* __restrict__ C3,
           long long aB, long long bB, long long cB, float scale) {
  __shared__ __align__(16) u16 As[4 * 8192];   // 64 KB: A k-half ring
  __shared__ __align__(16) u16 Bs[4 * 8192];   // 64 KB: B k-half ring

  // bijective XCD swizzle on flattened id (nwg % 8 == 0 for both call sites)
  const int gx = gridDim.x, gy = gridDim.y, gz = gridDim.z;
  const int flat = blockIdx.x + gx * (blockIdx.y + gy * blockIdx.z);
  const int nwg = gx * gy * gz;
  const int lg = (flat & 7) * (nwg >> 3) + (flat >> 3);
  const int bx = lg % gx;
  const int by = (lg / gx) % gy;
  const int bz = lg / (gx * gy);

  const int m0 = by * 256, n0 = bx * 256;
  const u16* pAhi = Ahi + (size_t)bz * aB;
  const u16* pAlo = Alo + (size_t)bz * aB;
  const u16* pBhi = Bhi + (size_t)bz * bB;
  const u16* pBlo = Blo + (size_t)bz * bB;

  const int tid = threadIdx.x;
  const int w = tid >> 6;             // wave 0..7
  const int L = tid & 63;
  const int rr = L & 15, quad = L >> 4;
  const int wm = (w >> 2) * 128;      // 0 / 128
  const int wn = (w & 3) * 64;        // 0 / 64 / 128 / 192

  // staging: lane covers row w*16 + (L>>2), phys chunk L&3; inverse-swizzled
  // global source chunk = (L&3) ^ s(row), s(row) = (row>>1)&3 = (L>>3)&3
  const int rbase = w * 16 + (L >> 2);
  const int coff = (((L & 3) ^ ((L >> 3) & 3)) << 3);
  const int arow = (m0 + rbase) * 1024 + coff;  // elem offset within one plane
  const int brow = (n0 + rbase) * 1024 + coff;
  u16* const ldA = As + w * 512;                // wave-uniform LDS dest base
  u16* const ldB = Bs + w * 512;

  // frag reads: row*32 + (quad ^ ((row>>1)&3))*8 ; (row>>1)&3 == (rr>>1)&3
  // for all frag rows (wm/wn/i*16 are 0 mod 8 after >>1)
  const int aoff = ((wm + rr) << 5) + ((quad ^ ((rr >> 1) & 3)) << 3);
  const int boff = ((wn + rr) << 5) + ((quad ^ ((rr >> 1) & 3)) << 3);

  auto stageA = [&](int H) {
    const int kt = H >> 1;
    const u16* src = (kt < 32) ? pAhi : pAlo;           // terms: hh, hl -> Ahi; lh -> Alo
    const int koff = ((kt & 15) << 6) + ((H & 1) << 5);
    const u16* g = src + arow + koff;
    u16* l = ldA + (H & 3) * 8192;
    gl_lds16(g, l);
    gl_lds16(g + 128 * 1024, l + 4096);
  };
  auto stageB = [&](int H) {
    const int kt = H >> 1;
    const u16* src = (kt < 16) ? pBhi : (kt < 32) ? pBlo : pBhi;
    const int koff = ((kt & 15) << 6) + ((H & 1) << 5);
    const u16* g = src + brow + koff;
    u16* l = ldB + (H & 3) * 8192;
    gl_lds16(g, l);
    gl_lds16(g + 128 * 1024, l + 4096);
  };

  floatx4 acc[8][4] = {};

#define PAIR(H, SB2, SA3, VM)                                                  \
  {                                                                            \
    __builtin_amdgcn_sched_barrier(0);                                         \
    const u16* ab = As + ((H) & 3) * 8192 + aoff;                              \
    const u16* bb = Bs + ((H) & 3) * 8192 + boff;                              \
    bf16x8 a[8], b0, b1, b2, b3;                                               \
    _Pragma("unroll")                                                          \
    for (int i = 0; i < 8; i++) a[i] = *(const bf16x8*)(ab + i * 512);         \
    b0 = *(const bf16x8*)(bb);                                                 \
    b1 = *(const bf16x8*)(bb + 512);                                           \
    b2 = *(const bf16x8*)(bb + 1024);                                          \
    b3 = *(const bf16x8*)(bb + 1536);                                          \
    if (SB2) stageB((H) + 2);                                                  \
    __builtin_amdgcn_s_barrier();                                              \
    asm volatile("s_waitcnt lgkmcnt(2)");                                      \
    __builtin_amdgcn_s_setprio(1);                                             \
    _Pragma("unroll")                                                          \
    for (int i = 0; i < 8; i++) {                                              \
      acc[i][0] = __builtin_amdgcn_mfma_f32_16x16x32_bf16(a[i], b0, acc[i][0], 0, 0, 0); \
      acc[i][1] = __builtin_amdgcn_mfma_f32_16x16x32_bf16(a[i], b1, acc[i][1], 0, 0, 0); \
    }                                                                          \
    __builtin_amdgcn_s_setprio(0);                                             \
    __builtin_amdgcn_s_barrier();                                              \
    if (SA3) stageA((H) + 3);                                                  \
    asm volatile("s_waitcnt lgkmcnt(0)");                                      \
    __builtin_amdgcn_s_setprio(1);                                             \
    _Pragma("unroll")                                                          \
    for (int i = 0; i < 8; i++) {                                              \
      acc[i][2] = __builtin_amdgcn_mfma_f32_16x16x32_bf16(a[i], b2, acc[i][2], 0, 0, 0); \
      acc[i][3] = __builtin_amdgcn_mfma_f32_16x16x32_bf16(a[i], b3, acc[i][3], 0, 0, 0); \
    }                                                                          \
    __builtin_amdgcn_s_setprio(0);                                             \
    if ((VM) == 6) asm volatile("s_waitcnt vmcnt(6)");                         \
    else if ((VM) == 4) asm volatile("s_waitcnt vmcnt(4)");                    \
    else if ((VM) == 0) asm volatile("s_waitcnt vmcnt(0)");                    \
    __builtin_amdgcn_s_barrier();                                              \
  }

  // prologue: issue order A0,B0,A1,B1,A2 -> 3 halves (6 loads) stay in flight
  stageA(0); stageB(0); stageA(1); stageB(1); stageA(2);
  asm volatile("s_waitcnt vmcnt(6)");
  __builtin_amdgcn_s_barrier();

  for (int H = 0; H <= 92; ++H)
    PAIR(H, true, true, 6);
  PAIR(93, true, false, 4);           // stages B(95) only; drain to 4
  PAIR(94, false, false, 0);          // drain to 0 (guarantees A(95),B(95))
  PAIR(95, false, false, -1);         // last pair, nothing to wait for
#undef PAIR

  // epilogue: D[row = quad*4+ii][col = rr] per 16x16 fragment (m89-verified)
#pragma unroll
  for (int i = 0; i < 8; i++) {
    const int mb = m0 + wm + i * 16 + quad * 4;
#pragma unroll
    for (int j = 0; j < 4; j++) {
      const int col = n0 + wn + j * 16 + rr;
      if (OM == 5) {
        u16* hi; u16* lo;
        if (col < 1024) { hi = (u16*)C0; lo = (u16*)C1; }
        else            { hi = (u16*)C2; lo = (u16*)C3; }
        const int cc = col & 1023;
        const float bvs = bias[col];
#pragma unroll
        for (int ii = 0; ii < 4; ii++) {
          const float v = acc[i][j][ii] + bvs;
          const size_t idx = (size_t)(mb + ii) * 1024 + cc;
          const u16 h = f2bf(v);
          hi[idx] = h;
          lo[idx] = f2bf(v - bf2f(h));
        }
      } else {
        float* Cf = (float*)C0 + (size_t)bz * cB;
#pragma unroll
        for (int ii = 0; ii < 4; ii++)
          Cf[(size_t)(mb + ii) * 2048 + col] = acc[i][j][ii] * scale;
      }
    }
  }
}

// ---------- row softmax over 2048 fp32 scores, in place + bf16 copy ------------
__global__ __launch_bounds__(256)
void softmax_rows(float* __restrict__ S, u16* __restrict__ Pb) {
  const int row = blockIdx.x;
  float* s = S + (size_t)row * 2048;
  const int tid = threadIdx.x;
  const int w = tid >> 6;
  __shared__ float redm[4];
  __shared__ float reds[4];

  float v[8];
  float mx = -1e30f;
#pragma unroll
  for (int i = 0; i < 8; i++) {
    v[i] = s[tid + 256 * i];
    mx = fmaxf(mx, v[i]);
  }
#pragma unroll
  for (int o = 32; o > 0; o >>= 1) mx = fmaxf(mx, __shfl_xor(mx, o, 64));
  if ((tid & 63) == 0) redm[w] = mx;
  __syncthreads();
  mx = fmaxf(fmaxf(redm[0], redm[1]), fmaxf(redm[2], redm[3]));

  float sum = 0.f;
#pragma unroll
  for (int i = 0; i < 8; i++) {
    v[i] = __expf(v[i] - mx);
    sum += v[i];
  }
#pragma unroll
  for (int o = 32; o > 0; o >>= 1) sum += __shfl_xor(sum, o, 64);
  if ((tid & 63) == 0) reds[w] = sum;
  __syncthreads();
  sum = reds[0] + reds[1] + reds[2] + reds[3];
  const float rs = 1.0f / sum;
#pragma unroll
  for (int i = 0; i < 8; i++) {
    const float p = v[i] * rs;
    s[tid + 256 * i] = p;
    Pb[(size_t)row * 2048 + tid + 256 * i] = f2bf(p);
  }
}

// ---------- launch ------------------------------------------------------------
extern "C" void kernel_launch(void* const* d_in, const int* in_sizes, int n_in,
                              void* d_out, int out_size, void* d_ws, size_t ws_size,
                              hipStream_t stream) {
  const float* x  = (const float*)d_in[0];
  const float* wq = (const float*)d_in[1];
  const float* bq = (const float*)d_in[2];
  const float* wk = (const float*)d_in[3];
  const float* bk = (const float*)d_in[4];
  const float* wv = (const float*)d_in[5];
  const float* bv = (const float*)d_in[6];
  const float* wp = (const float*)d_in[7];
  const float* bp = (const float*)d_in[8];

  const size_t MB = 1024 * 1024;
  char* ws = (char*)d_ws;
  u16* qkThi = (u16*)(ws + 0 * MB);          // [2048][1024] bf16, 4 MB
  u16* qkTlo = (u16*)(ws + 4 * MB);          // 4 MB
  u16* wvThi = (u16*)(ws + 8 * MB);          // 2 MB
  u16* wpThi = (u16*)(ws + 10 * MB);         // 2 MB
  float* bqk = (float*)(ws + 12 * MB);       // 8 KB
  u16* xhi   = (u16*)(ws + 13 * MB);         // 16 MB each (8192x1024 bf16)
  u16* xlo   = (u16*)(ws + 29 * MB);
  u16* qhi   = (u16*)(ws + 45 * MB);
  u16* qlo   = (u16*)(ws + 61 * MB);
  u16* khi   = (u16*)(ws + 77 * MB);
  u16* klo   = (u16*)(ws + 93 * MB);
  u16* xThi  = (u16*)(ws + 109 * MB);        // [b][1024][2048] bf16, 16 MB
  u16* pbf   = khi;                          // overlay: k dead after scores
  u16* px    = qhi;                          // overlay: q dead after scores
  u16* ctx   = qlo;                          // overlay

  float* outp = (float*)d_out;               // [4,2048,1024] fp32
  float* scf  = (float*)d_out + 8388608;     // scores -> softmax in place

  const dim3 blk(256);

  // prep: weights + bias + x split/transpose, one launch
  prep_all<<<dim3(32, 32, 13), blk, 0, stream>>>(
      wq, wk, wv, wp, bq, bk, x, qkThi, qkTlo, wvThi, wpThi, bqk, xhi, xlo, xThi);

  // fused Q|K projection: 256^2 8-phase, K-extended 3-term split, routed planar
  // split outputs. 256 blocks = 1/CU.
  gemm8<5><<<dim3(8, 32, 1), dim3(512), 0, stream>>>(
      xhi, xlo, qkThi, qkTlo, bqk, qhi, qlo, khi, klo, 0, 0, 0, 1.0f);

  // scores = (q . k) * 32, 256^2 8-phase, fp32 into d_out's p region
  gemm8<2><<<dim3(8, 8, 4), dim3(512), 0, stream>>>(
      qhi, qlo, khi, klo, nullptr, scf, nullptr, nullptr, nullptr,
      2048LL * 1024, 2048LL * 1024, 2048LL * 2048, 32.0f);

  // softmax rows: fp32 p in place (d_out) + bf16 p
  softmax_rows<<<dim3(8192), blk, 0, stream>>>(scf, pbf);

  // px = p @ x   (reassociation: ctx = (p@x)@wv + bv since rows of p sum to 1)
  gemm_mfma<64, 0, 0, 0, 0><<<dim3(8, 16, 4), blk, 0, stream>>>(
      pbf, nullptr, xThi, nullptr, nullptr, px, nullptr, nullptr, nullptr,
      1024, 2048, 2048, 2048, 1024,
      2048LL * 2048, 1024LL * 2048, 2048LL * 1024, 1.0f);

  // ctx = px @ wv + bv (bf16 out)
  gemm_mfma<64, 0, 0, 0, 1><<<dim3(8, 64, 1), blk, 0, stream>>>(
      px, nullptr, wvThi, nullptr, bv, ctx, nullptr, nullptr, nullptr,
      1024, 1024, 1024, 1024, 1024, 0, 0, 0, 1.0f);

  // output = ctx @ wp + bp, fp32 out
  gemm_mfma<64, 0, 0, 2, 1><<<dim3(8, 64, 1), blk, 0, stream>>>(
      ctx, nullptr, wpThi, nullptr, bp, outp, nullptr, nullptr, nullptr,
      1024, 1024, 1024, 1024, 1024, 0, 0, 0, 1.0f);
}

// Round 3
// 436.827 us; speedup vs baseline: 1.1927x; 1.0388x over previous
//
#include <hip/hip_runtime.h>

typedef unsigned short u16;
typedef short bf16x8 __attribute__((ext_vector_type(8)));
typedef float floatx4 __attribute__((ext_vector_type(4)));

// ---------- bf16 helpers (bit-level RNE) --------------------------------------
static __device__ __forceinline__ u16 f2bf(float f) {
  unsigned int u = __float_as_uint(f);
  unsigned int lsb = (u >> 16) & 1u;
  u += 0x7FFFu + lsb;                 // round-to-nearest-even
  return (u16)(u >> 16);
}
static __device__ __forceinline__ float bf2f(u16 u) {
  return __uint_as_float(((unsigned int)u) << 16);
}

// ---------- async global->LDS, 16B per lane (dest = uniform base + lane*16) ----
static __device__ __forceinline__ void gl_lds16(const u16* g, u16* l) {
  __builtin_amdgcn_global_load_lds(
      (const __attribute__((address_space(1))) void*)g,
      (__attribute__((address_space(3))) void*)l, 16, 0, 0);
}

// ---------- unified prep: weight transposes + bias concat + x split/transpose --
__global__ __launch_bounds__(256)
void prep_all(const float* __restrict__ wq, const float* __restrict__ wk,
              const float* __restrict__ wv, const float* __restrict__ wp,
              const float* __restrict__ bq, const float* __restrict__ bk,
              const float* __restrict__ x,
              u16* __restrict__ qkThi, u16* __restrict__ qkTlo,
              u16* __restrict__ wvThi, u16* __restrict__ wpThi,
              float* __restrict__ bqk,
              u16* __restrict__ xhi, u16* __restrict__ xlo,
              u16* __restrict__ xThi) {
  __shared__ float t[32][33];
  const int z = blockIdx.z;
  const int tid = threadIdx.x;
  const int lr = tid >> 3;            // 0..31
  const int lc = (tid & 7) * 4;       // 0,4,..,28

  if (z == 4) {
    if (blockIdx.y == 0 && blockIdx.x < 8) {
      const int i = blockIdx.x * 256 + tid;
      bqk[i] = (i < 1024) ? bq[i] : bk[i - 1024];
    }
    return;
  }

  if (z >= 5) {
    const int r0 = ((z - 5) * 32 + blockIdx.y) * 32;
    const int c0 = blockIdx.x * 32;
    float4 v = *(const float4*)(x + (size_t)(r0 + lr) * 1024 + c0 + lc);
    float f[4] = {v.x, v.y, v.z, v.w};
    t[lr][lc + 0] = v.x; t[lr][lc + 1] = v.y; t[lr][lc + 2] = v.z; t[lr][lc + 3] = v.w;
    u16 ph[4], pl[4];
#pragma unroll
    for (int j = 0; j < 4; j++) {
      ph[j] = f2bf(f[j]);
      pl[j] = f2bf(f[j] - bf2f(ph[j]));
    }
    const size_t o = (size_t)(r0 + lr) * 1024 + c0 + lc;
    *(uint2*)(xhi + o) = *(uint2*)ph;
    *(uint2*)(xlo + o) = *(uint2*)pl;
    __syncthreads();
    u16 pt[4];
#pragma unroll
    for (int j = 0; j < 4; j++) pt[j] = f2bf(t[lc + j][lr]);
    const int b = r0 >> 11, rt = r0 & 2047;
    *(uint2*)(xThi + (size_t)b * (1024 * 2048) + (size_t)(c0 + lr) * 2048 + rt + lc) =
        *(uint2*)pt;
    return;
  }

  // weight transposes (z 0..3)
  const float* in = (z == 0) ? wq : (z == 1) ? wk : (z == 2) ? wv : wp;
  u16* hi = (z == 2) ? wvThi : (z == 3) ? wpThi : (qkThi + (size_t)z * 1024 * 1024);
  u16* lo = (z == 0) ? qkTlo : (z == 1) ? (qkTlo + 1024 * 1024) : (u16*)nullptr;
  const int want_lo = (z < 2);

  const int r0 = blockIdx.y * 32, c0 = blockIdx.x * 32;
  float4 v = *(const float4*)(in + (size_t)(r0 + lr) * 1024 + c0 + lc);
  t[lr][lc + 0] = v.x; t[lr][lc + 1] = v.y; t[lr][lc + 2] = v.z; t[lr][lc + 3] = v.w;
  __syncthreads();
  u16 ph[4], pl[4];
#pragma unroll
  for (int j = 0; j < 4; j++) {
    float f = t[lc + j][lr];
    ph[j] = f2bf(f);
    if (want_lo) pl[j] = f2bf(f - bf2f(ph[j]));
  }
  const size_t o = (size_t)(c0 + lr) * 1024 + r0 + lc;
  *(uint2*)(hi + o) = *(uint2*)ph;
  if (want_lo) *(uint2*)(lo + o) = *(uint2*)pl;
}

// ---------- MFMA GEMM, m97 structure (kept for px / ctx / output GEMMs) --------
template<int KB, int ASP, int BSP, int OM, int HB>
__global__ __launch_bounds__(256)
void gemm_mfma(const u16* __restrict__ Ahi, const u16* __restrict__ Alo,
               const u16* __restrict__ Bhi, const u16* __restrict__ Blo,
               const float* __restrict__ bias,
               void* __restrict__ C0, void* __restrict__ C1,
               void* __restrict__ C2, void* __restrict__ C3,
               int N, int K, int lda, int ldb, int ldc,
               long long aB, long long bB, long long cB, float scale) {
  constexpr int CM = KB / 8 - 1;
  constexpr int RPI = 512 / KB;
  constexpr int NI = KB / 16;
  constexpr int PL = 128 * KB;
  __shared__ __align__(16) u16 As[(1 + ASP) * PL];
  __shared__ __align__(16) u16 Bs[(1 + BSP) * PL];

  const int bz = blockIdx.z;
  const u16* A0 = Ahi + (size_t)bz * aB;
  const u16* A1 = ASP ? (Alo + (size_t)bz * aB) : (const u16*)nullptr;
  const u16* B0 = Bhi + (size_t)bz * bB;
  const u16* B1 = BSP ? (Blo + (size_t)bz * bB) : (const u16*)nullptr;

  const int m0 = blockIdx.y * 128;
  const int n0 = blockIdx.x * 128;
  const int tid = threadIdx.x;
  const int w = tid >> 6;
  const int L = tid & 63;
  const int rr = L & 15, quad = L >> 4;
  const int wm = (w >> 1) * 64, wn = (w & 1) * 64;

  const int lrow = (KB == 32) ? (L >> 2) : (L >> 3);
  const int c3 = (L & CM) ^ ((L >> 3) & CM);
  const int srow = w * 32 + lrow;
  u16* stA = &As[w * 32 * KB];
  u16* stB = &Bs[w * 32 * KB];
  const u16* gA0 = A0 + (size_t)(m0 + srow) * lda + c3 * 8;
  const u16* gA1 = ASP ? A1 + (size_t)(m0 + srow) * lda + c3 * 8 : (const u16*)nullptr;
  const u16* gB0 = B0 + (size_t)(n0 + srow) * ldb + c3 * 8;
  const u16* gB1 = BSP ? B1 + (size_t)(n0 + srow) * ldb + c3 * 8 : (const u16*)nullptr;

  floatx4 acc[4][4] = {};

  for (int k0 = 0; k0 < K; k0 += KB) {
#pragma unroll
    for (int q = 0; q < NI; q++) {
      gl_lds16(gA0 + k0 + (size_t)q * RPI * lda, stA + q * 512);
      gl_lds16(gB0 + k0 + (size_t)q * RPI * ldb, stB + q * 512);
    }
    if (ASP) {
#pragma unroll
      for (int q = 0; q < NI; q++)
        gl_lds16(gA1 + k0 + (size_t)q * RPI * lda, stA + PL + q * 512);
    }
    if (BSP) {
#pragma unroll
      for (int q = 0; q < NI; q++)
        gl_lds16(gB1 + k0 + (size_t)q * RPI * ldb, stB + PL + q * 512);
    }
    __syncthreads();

#pragma unroll
    for (int s = 0; s < KB / 32; s++) {
      const int pcb = ((KB == 32) ? (quad ^ ((rr >> 1) & 3))
                                  : ((s * 4 + quad) ^ (rr & 7))) * 8;
      bf16x8 a0[4], a1[4], b0[4], b1[4];
#pragma unroll
      for (int i = 0; i < 4; i++) {
        const int arow = wm + i * 16 + rr;
        const int brow = wn + i * 16 + rr;
        a0[i] = *(const bf16x8*)&As[arow * KB + pcb];
        b0[i] = *(const bf16x8*)&Bs[brow * KB + pcb];
        if (ASP) a1[i] = *(const bf16x8*)&As[PL + arow * KB + pcb];
        if (BSP) b1[i] = *(const bf16x8*)&Bs[PL + brow * KB + pcb];
      }
#pragma unroll
      for (int i = 0; i < 4; i++) {
#pragma unroll
        for (int j = 0; j < 4; j++) {
          acc[i][j] = __builtin_amdgcn_mfma_f32_16x16x32_bf16(a0[i], b0[j], acc[i][j], 0, 0, 0);
          if (ASP && BSP) {
            acc[i][j] = __builtin_amdgcn_mfma_f32_16x16x32_bf16(a0[i], b1[j], acc[i][j], 0, 0, 0);
            acc[i][j] = __builtin_amdgcn_mfma_f32_16x16x32_bf16(a1[i], b0[j], acc[i][j], 0, 0, 0);
          }
        }
      }
    }
    __syncthreads();
  }

#pragma unroll
  for (int i = 0; i < 4; i++) {
    const int mbase = m0 + wm + i * 16 + quad * 4;
#pragma unroll
    for (int j = 0; j < 4; j++) {
      const int col = n0 + wn + j * 16 + rr;
      float bvs = 0.f;
      if (HB) bvs = bias[col];
      if (OM == 5) {
        u16* hi; u16* lo;
        if (col < 1024) { hi = (u16*)C0; lo = (u16*)C1; }
        else            { hi = (u16*)C2; lo = (u16*)C3; }
        const int cc = col & 1023;
#pragma unroll
        for (int ii = 0; ii < 4; ii++) {
          const float v = acc[i][j][ii] + bvs;
          const size_t idx = (size_t)(mbase + ii) * 1024 + cc;
          const u16 h = f2bf(v);
          hi[idx] = h;
          lo[idx] = f2bf(v - bf2f(h));
        }
      } else {
        u16* Cb = (u16*)C0 + (size_t)bz * cB;
        float* Cf = (float*)C0 + (size_t)bz * cB;
        u16* Cl = (OM == 1) ? ((u16*)C1 + (size_t)bz * cB) : (u16*)nullptr;
#pragma unroll
        for (int ii = 0; ii < 4; ii++) {
          const float v = acc[i][j][ii] * scale + bvs;
          const size_t idx = (size_t)(mbase + ii) * ldc + col;
          if (OM == 0) {
            Cb[idx] = f2bf(v);
          } else if (OM == 1) {
            const u16 h = f2bf(v);
            Cb[idx] = h;
            Cl[idx] = f2bf(v - bf2f(h));
          } else {
            Cf[idx] = v;
          }
        }
      }
    }
  }
}

// ---------- 256x256 pipelined GEMM, 3-term split via K-extension ---------------
// C[M,N] = Ahi.Bhi^T + Ahi.Blo^T + Alo.Bhi^T, A/B stored [rows][1024] bf16.
// K_eff = 3072 = 96 k-halves of 32 (pairs H = 0..95).
// R3 change: register-level pipelining. Phase 1 of pair H reads b23 (slot H,
// consumed phase 2 under cluster-1 MFMA cover); phase 2 reads a[8]+b01 of slot
// H+1 (consumed next pair's cluster 1 under cluster-2 cover). ds_read latency
// fully hidden; 1 barrier/pair (was 3). Even/odd reg sets avoid dyn indexing
// (rule #20); sched_barrier(0) pins issue order.
// LDS ring: 4 half-slots/operand, swizzle phys chunk = logical ^ ((row>>1)&3)
// (2-way = free, R2-verified 0 conflicts); source inverse-swizzled (rule #21).
// vmcnt: invariant "slot H+2 complete at end of pair H" -> steady vmcnt(2),
// never 0 in main loop; prologue vmcnt(2); tail 2 -> 0.
template<int OM>
__global__ __launch_bounds__(512, 2)
void gemm8(const u16* __restrict__ Ahi, const u16* __restrict__ Alo,
           const u16* __restrict__ Bhi, const u16* __restrict__ Blo,
           const float* __restrict__ bias,
           void* __restrict__ C0, void* __restrict__ C1,
           void* __restrict__ C2, void* __restrict__ C3,
           long long aB, long long bB, long long cB, float scale) {
  __shared__ __align__(16) u16 As[4 * 8192];   // 64 KB: A k-half ring
  __shared__ __align__(16) u16 Bs[4 * 8192];   // 64 KB: B k-half ring

  // bijective XCD swizzle on flattened id (nwg % 8 == 0 for both call sites)
  const int gx = gridDim.x, gy = gridDim.y, gz = gridDim.z;
  const int flat = blockIdx.x + gx * (blockIdx.y + gy * blockIdx.z);
  const int nwg = gx * gy * gz;
  const int lg = (flat & 7) * (nwg >> 3) + (flat >> 3);
  const int bx = lg % gx;
  const int by = (lg / gx) % gy;
  const int bz = lg / (gx * gy);

  const int m0 = by * 256, n0 = bx * 256;
  const u16* pAhi = Ahi + (size_t)bz * aB;
  const u16* pAlo = Alo + (size_t)bz * aB;
  const u16* pBhi = Bhi + (size_t)bz * bB;
  const u16* pBlo = Blo + (size_t)bz * bB;

  const int tid = threadIdx.x;
  const int w = tid >> 6;             // wave 0..7
  const int L = tid & 63;
  const int rr = L & 15, quad = L >> 4;
  const int wm = (w >> 2) * 128;      // 0 / 128
  const int wn = (w & 3) * 64;        // 0 / 64 / 128 / 192

  // staging: lane covers row w*16 + (L>>2), phys chunk L&3; inverse-swizzled
  // global source chunk = (L&3) ^ s(row), s(row) = (row>>1)&3 = (L>>3)&3
  const int rbase = w * 16 + (L >> 2);
  const int coff = (((L & 3) ^ ((L >> 3) & 3)) << 3);
  const int arow = (m0 + rbase) * 1024 + coff;  // elem offset within one plane
  const int brow = (n0 + rbase) * 1024 + coff;
  u16* const ldA = As + w * 512;                // wave-uniform LDS dest base
  u16* const ldB = Bs + w * 512;

  // frag reads: row*32 + (quad ^ ((row>>1)&3))*8 ; (row>>1)&3 == (rr>>1)&3
  const int aoff = ((wm + rr) << 5) + ((quad ^ ((rr >> 1) & 3)) << 3);
  const int boff = ((wn + rr) << 5) + ((quad ^ ((rr >> 1) & 3)) << 3);

  auto stageA = [&](int H) {
    const int kt = H >> 1;
    const u16* src = (kt < 32) ? pAhi : pAlo;           // hh, hl -> Ahi; lh -> Alo
    const int koff = ((kt & 15) << 6) + ((H & 1) << 5);
    const u16* g = src + arow + koff;
    u16* l = ldA + (H & 3) * 8192;
    gl_lds16(g, l);
    gl_lds16(g + 128 * 1024, l + 4096);
  };
  auto stageB = [&](int H) {
    const int kt = H >> 1;
    const u16* src = (kt < 16) ? pBhi : (kt < 32) ? pBlo : pBhi;
    const int koff = ((kt & 15) << 6) + ((H & 1) << 5);
    const u16* g = src + brow + koff;
    u16* l = ldB + (H & 3) * 8192;
    gl_lds16(g, l);
    gl_lds16(g + 128 * 1024, l + 4096);
  };

  floatx4 acc[8][4] = {};
  bf16x8 aE[8], aO[8], b01E[2], b01O[2], b23[2];

#define RD_SET(slot, A_, B_)                                                   \
  {                                                                            \
    const u16* ab_ = As + ((slot) & 3) * 8192 + aoff;                          \
    const u16* bb_ = Bs + ((slot) & 3) * 8192 + boff;                          \
    _Pragma("unroll")                                                          \
    for (int i = 0; i < 8; i++) A_[i] = *(const bf16x8*)(ab_ + i * 512);       \
    B_[0] = *(const bf16x8*)(bb_);                                             \
    B_[1] = *(const bf16x8*)(bb_ + 512);                                       \
  }

#define PAIRX(H, AC, B01C, AN, B01N, SB2, SA3, RDN, VM)                        \
  {                                                                            \
    __builtin_amdgcn_sched_barrier(0);                                         \
    {                                                                          \
      const u16* bb_ = Bs + ((H) & 3) * 8192 + boff;                           \
      b23[0] = *(const bf16x8*)(bb_ + 1024);                                   \
      b23[1] = *(const bf16x8*)(bb_ + 1536);                                   \
    }                                                                          \
    if (SB2) stageB((H) + 2);                                                  \
    __builtin_amdgcn_sched_barrier(0);                                         \
    __builtin_amdgcn_s_setprio(1);                                             \
    _Pragma("unroll")                                                          \
    for (int i = 0; i < 8; i++) {                                              \
      acc[i][0] = __builtin_amdgcn_mfma_f32_16x16x32_bf16(AC[i], B01C[0], acc[i][0], 0, 0, 0); \
      acc[i][1] = __builtin_amdgcn_mfma_f32_16x16x32_bf16(AC[i], B01C[1], acc[i][1], 0, 0, 0); \
    }                                                                          \
    __builtin_amdgcn_s_setprio(0);                                             \
    __builtin_amdgcn_sched_barrier(0);                                         \
    if (RDN) RD_SET((H) + 1, AN, B01N);                                        \
    if (SA3) stageA((H) + 3);                                                  \
    __builtin_amdgcn_sched_barrier(0);                                         \
    __builtin_amdgcn_s_setprio(1);                                             \
    _Pragma("unroll")                                                          \
    for (int i = 0; i < 8; i++) {                                              \
      acc[i][2] = __builtin_amdgcn_mfma_f32_16x16x32_bf16(AC[i], b23[0], acc[i][2], 0, 0, 0); \
      acc[i][3] = __builtin_amdgcn_mfma_f32_16x16x32_bf16(AC[i], b23[1], acc[i][3], 0, 0, 0); \
    }                                                                          \
    __builtin_amdgcn_s_setprio(0);                                             \
    if ((VM) == 2) asm volatile("s_waitcnt vmcnt(2)");                         \
    else if ((VM) == 0) asm volatile("s_waitcnt vmcnt(0)");                    \
    __builtin_amdgcn_s_barrier();                                              \
  }

  // prologue: A0,B0,A1,B1,A2 in flight; vmcnt(2) completes slots 0,1 (leaves A2)
  stageA(0); stageB(0); stageA(1); stageB(1); stageA(2);
  asm volatile("s_waitcnt vmcnt(2)");
  __builtin_amdgcn_s_barrier();
  RD_SET(0, aE, b01E);                // pair 0's cluster-1 operands

  for (int H = 0; H < 92; H += 2) {
    PAIRX(H,     aE, b01E, aO, b01O, true, true, true, 2);
    PAIRX(H + 1, aO, b01O, aE, b01E, true, true, true, 2);
  }
  PAIRX(92, aE, b01E, aO, b01O, true,  true,  true,  2);   // B94, A95; slot94 done
  PAIRX(93, aO, b01O, aE, b01E, true,  false, true,  0);   // B95; drain all
  PAIRX(94, aE, b01E, aO, b01O, false, false, true,  -1);  // read slot95
  PAIRX(95, aO, b01O, aE, b01E, false, false, false, -1);
#undef PAIRX
#undef RD_SET

  // epilogue: D[row = quad*4+ii][col = rr] per 16x16 fragment (m89-verified)
#pragma unroll
  for (int i = 0; i < 8; i++) {
    const int mb = m0 + wm + i * 16 + quad * 4;
#pragma unroll
    for (int j = 0; j < 4; j++) {
      const int col = n0 + wn + j * 16 + rr;
      if (OM == 5) {
        u16* hi; u16* lo;
        if (col < 1024) { hi = (u16*)C0; lo = (u16*)C1; }
        else            { hi = (u16*)C2; lo = (u16*)C3; }
        const int cc = col & 1023;
        const float bvs = bias[col];
#pragma unroll
        for (int ii = 0; ii < 4; ii++) {
          const float v = acc[i][j][ii] + bvs;
          const size_t idx = (size_t)(mb + ii) * 1024 + cc;
          const u16 h = f2bf(v);
          hi[idx] = h;
          lo[idx] = f2bf(v - bf2f(h));
        }
      } else {
        float* Cf = (float*)C0 + (size_t)bz * cB;
#pragma unroll
        for (int ii = 0; ii < 4; ii++)
          Cf[(size_t)(mb + ii) * 2048 + col] = acc[i][j][ii] * scale;
      }
    }
  }
}

// ---------- row softmax over 2048 fp32 scores, in place + bf16 copy ------------
__global__ __launch_bounds__(256)
void softmax_rows(float* __restrict__ S, u16* __restrict__ Pb) {
  const int row = blockIdx.x;
  float* s = S + (size_t)row * 2048;
  const int tid = threadIdx.x;
  const int w = tid >> 6;
  __shared__ float redm[4];
  __shared__ float reds[4];

  float v[8];
  float mx = -1e30f;
#pragma unroll
  for (int i = 0; i < 8; i++) {
    v[i] = s[tid + 256 * i];
    mx = fmaxf(mx, v[i]);
  }
#pragma unroll
  for (int o = 32; o > 0; o >>= 1) mx = fmaxf(mx, __shfl_xor(mx, o, 64));
  if ((tid & 63) == 0) redm[w] = mx;
  __syncthreads();
  mx = fmaxf(fmaxf(redm[0], redm[1]), fmaxf(redm[2], redm[3]));

  float sum = 0.f;
#pragma unroll
  for (int i = 0; i < 8; i++) {
    v[i] = __expf(v[i] - mx);
    sum += v[i];
  }
#pragma unroll
  for (int o = 32; o > 0; o >>= 1) sum += __shfl_xor(sum, o, 64);
  if ((tid & 63) == 0) reds[w] = sum;
  __syncthreads();
  sum = reds[0] + reds[1] + reds[2] + reds[3];
  const float rs = 1.0f / sum;
#pragma unroll
  for (int i = 0; i < 8; i++) {
    const float p = v[i] * rs;
    s[tid + 256 * i] = p;
    Pb[(size_t)row * 2048 + tid + 256 * i] = f2bf(p);
  }
}

// ---------- launch ------------------------------------------------------------
extern "C" void kernel_launch(void* const* d_in, const int* in_sizes, int n_in,
                              void* d_out, int out_size, void* d_ws, size_t ws_size,
                              hipStream_t stream) {
  const float* x  = (const float*)d_in[0];
  const float* wq = (const float*)d_in[1];
  const float* bq = (const float*)d_in[2];
  const float* wk = (const float*)d_in[3];
  const float* bk = (const float*)d_in[4];
  const float* wv = (const float*)d_in[5];
  const float* bv = (const float*)d_in[6];
  const float* wp = (const float*)d_in[7];
  const float* bp = (const float*)d_in[8];

  const size_t MB = 1024 * 1024;
  char* ws = (char*)d_ws;
  u16* qkThi = (u16*)(ws + 0 * MB);          // [2048][1024] bf16, 4 MB
  u16* qkTlo = (u16*)(ws + 4 * MB);          // 4 MB
  u16* wvThi = (u16*)(ws + 8 * MB);          // 2 MB
  u16* wpThi = (u16*)(ws + 10 * MB);         // 2 MB
  float* bqk = (float*)(ws + 12 * MB);       // 8 KB
  u16* xhi   = (u16*)(ws + 13 * MB);         // 16 MB each (8192x1024 bf16)
  u16* xlo   = (u16*)(ws + 29 * MB);
  u16* qhi   = (u16*)(ws + 45 * MB);
  u16* qlo   = (u16*)(ws + 61 * MB);
  u16* khi   = (u16*)(ws + 77 * MB);
  u16* klo   = (u16*)(ws + 93 * MB);
  u16* xThi  = (u16*)(ws + 109 * MB);        // [b][1024][2048] bf16, 16 MB
  u16* pbf   = khi;                          // overlay: k dead after scores
  u16* px    = qhi;                          // overlay: q dead after scores
  u16* ctx   = qlo;                          // overlay

  float* outp = (float*)d_out;               // [4,2048,1024] fp32
  float* scf  = (float*)d_out + 8388608;     // scores -> softmax in place

  const dim3 blk(256);

  // prep: weights + bias + x split/transpose, one launch
  prep_all<<<dim3(32, 32, 13), blk, 0, stream>>>(
      wq, wk, wv, wp, bq, bk, x, qkThi, qkTlo, wvThi, wpThi, bqk, xhi, xlo, xThi);

  // fused Q|K projection: 256^2 pipelined, K-extended 3-term split, routed
  // planar split outputs. 256 blocks = 1/CU.
  gemm8<5><<<dim3(8, 32, 1), dim3(512), 0, stream>>>(
      xhi, xlo, qkThi, qkTlo, bqk, qhi, qlo, khi, klo, 0, 0, 0, 1.0f);

  // scores = (q . k) * 32, 256^2 pipelined, fp32 into d_out's p region
  gemm8<2><<<dim3(8, 8, 4), dim3(512), 0, stream>>>(
      qhi, qlo, khi, klo, nullptr, scf, nullptr, nullptr, nullptr,
      2048LL * 1024, 2048LL * 1024, 2048LL * 2048, 32.0f);

  // softmax rows: fp32 p in place (d_out) + bf16 p
  softmax_rows<<<dim3(8192), blk, 0, stream>>>(scf, pbf);

  // px = p @ x   (reassociation: ctx = (p@x)@wv + bv since rows of p sum to 1)
  gemm_mfma<64, 0, 0, 0, 0><<<dim3(8, 16, 4), blk, 0, stream>>>(
      pbf, nullptr, xThi, nullptr, nullptr, px, nullptr, nullptr, nullptr,
      1024, 2048, 2048, 2048, 1024,
      2048LL * 2048, 1024LL * 2048, 2048LL * 1024, 1.0f);

  // ctx = px @ wv + bv (bf16 out)
  gemm_mfma<64, 0, 0, 0, 1><<<dim3(8, 64, 1), blk, 0, stream>>>(
      px, nullptr, wvThi, nullptr, bv, ctx, nullptr, nullptr, nullptr,
      1024, 1024, 1024, 1024, 1024, 0, 0, 0, 1.0f);

  // output = ctx @ wp + bp, fp32 out
  gemm_mfma<64, 0, 0, 2, 1><<<dim3(8, 64, 1), blk, 0, stream>>>(
      ctx, nullptr, wpThi, nullptr, bp, outp, nullptr, nullptr, nullptr,
      1024, 1024, 1024, 1024, 1024, 0, 0, 0, 1.0f);
}